// Round 1
// baseline (107.577 us; speedup 1.0000x reference)
//
#include <hip/hip_runtime.h>
#include <hip/hip_bf16.h>

#define NCLS 200
#define NPAD 208
#define NT 13          // 208 / 16 class tiles
#define DIM 512
#define NSAMP 32768

typedef __attribute__((ext_vector_type(4))) float f32x4;
typedef __attribute__((ext_vector_type(8))) short bf16x8;

__device__ inline short bf16s(float x) {
  __hip_bfloat16 h = __float2bfloat16(x);
  return *reinterpret_cast<short*>(&h);
}

// ---------------- Kernel 1: per-class prototypes (segment mean) ----------------
// One block per class (208 blocks; 200..207 are padding classes).
// Deterministic: ballot-based ordered match list, fixed accumulation order.
__global__ __launch_bounds__(256) void k_proto(
    const float* __restrict__ feat, const int* __restrict__ labels,
    unsigned short* __restrict__ protoB, float* __restrict__ p2out)
{
  const int c = blockIdx.x;
  const int tid = threadIdx.x;
  if (c >= NCLS) {
    protoB[c * DIM + tid] = 0;        // bf16 +0.0
    protoB[c * DIM + 256 + tid] = 0;
    if (tid == 0) p2out[c] = 1e30f;   // never wins argmin
    return;
  }
  __shared__ int lidx[512];
  __shared__ int wcnt[4];
  __shared__ float red[256];
  const int lane = tid & 63;
  const int w = tid >> 6;
  int total = 0;

  // phase 1: build ordered list of rows with label == c
  for (int i = 0; i < NSAMP / 256; ++i) {
    const int row = i * 256 + tid;
    const bool m = (labels[row] == c);
    const unsigned long long bal = __ballot(m);
    __syncthreads();
    if (lane == 0) wcnt[w] = __popcll(bal);
    __syncthreads();
    const int w0 = wcnt[0], w1 = wcnt[1], w2 = wcnt[2], w3 = wcnt[3];
    int pre = total;
    if (w > 0) pre += w0;
    if (w > 1) pre += w1;
    if (w > 2) pre += w2;
    if (m) {
      const int r = pre + __popcll(bal & ((1ull << lane) - 1ull));
      if (r < 512) lidx[r] = row;
    }
    total += w0 + w1 + w2 + w3;
  }
  __syncthreads();
  if (total > 512) total = 512;

  // phase 2: accumulate matching rows; thread owns dims tid and tid+256
  float acc0 = 0.f, acc1 = 0.f;
  int j = 0;
  for (; j + 8 <= total; j += 8) {
    int rr[8];
    #pragma unroll
    for (int u = 0; u < 8; ++u) rr[u] = lidx[j + u];
    float va[8], vb[8];
    #pragma unroll
    for (int u = 0; u < 8; ++u) {
      va[u] = feat[(size_t)rr[u] * DIM + tid];
      vb[u] = feat[(size_t)rr[u] * DIM + 256 + tid];
    }
    #pragma unroll
    for (int u = 0; u < 8; ++u) { acc0 += va[u]; acc1 += vb[u]; }
  }
  for (; j < total; ++j) {
    const int r = lidx[j];
    acc0 += feat[(size_t)r * DIM + tid];
    acc1 += feat[(size_t)r * DIM + 256 + tid];
  }

  const float inv = 1.0f / ((float)total + 1e-8f);  // counts + EPS
  const float p0 = acc0 * inv, p1 = acc1 * inv;
  protoB[c * DIM + tid] = (unsigned short)bf16s(p0);
  protoB[c * DIM + 256 + tid] = (unsigned short)bf16s(p1);

  red[tid] = p0 * p0 + p1 * p1;   // p2 from fp32 prototypes (matches reference)
  __syncthreads();
  for (int s = 128; s > 0; s >>= 1) {
    if (tid < s) red[tid] += red[tid + s];
    __syncthreads();
  }
  if (tid == 0) p2out[c] = red[0];
}

// ---------------- Kernel 2: scores (MFMA GEMM) + argmin + per-sample loss ------
// 1024 waves; each wave: 32 samples (2 x 16-row tiles) x 208 classes.
// A = features (fp32 loaded, bf16 in-register), B = bf16 prototypes, f2 on the fly.
__global__ __launch_bounds__(256) void k_score(
    const float* __restrict__ feat, const int* __restrict__ labels,
    const unsigned short* __restrict__ protoB, const float* __restrict__ p2,
    float* __restrict__ partials)
{
  const int tid = threadIdx.x;
  const int lane = tid & 63;
  const int wid = blockIdx.x * 4 + (tid >> 6);   // 0..1023
  const int base = wid * 32;
  const int lr = lane & 15;    // A row / B col (local)
  const int kg = lane >> 4;    // k-group

  f32x4 acc0[NT], acc1[NT];
  #pragma unroll
  for (int t = 0; t < NT; ++t) {
    acc0[t] = f32x4{0.f, 0.f, 0.f, 0.f};
    acc1[t] = f32x4{0.f, 0.f, 0.f, 0.f};
  }
  float f2a = 0.f, f2b = 0.f;

  const float* arow0 = feat + (size_t)(base + lr) * DIM;
  const float* arow1 = arow0 + 16 * DIM;

  for (int k = 0; k < 16; ++k) {
    const int koff = k * 32 + kg * 8;
    const f32x4 fa0 = *(const f32x4*)(arow0 + koff);
    const f32x4 fa1 = *(const f32x4*)(arow0 + koff + 4);
    const f32x4 fb0 = *(const f32x4*)(arow1 + koff);
    const f32x4 fb1 = *(const f32x4*)(arow1 + koff + 4);

    f2a += fa0[0]*fa0[0] + fa0[1]*fa0[1] + fa0[2]*fa0[2] + fa0[3]*fa0[3]
         + fa1[0]*fa1[0] + fa1[1]*fa1[1] + fa1[2]*fa1[2] + fa1[3]*fa1[3];
    f2b += fb0[0]*fb0[0] + fb0[1]*fb0[1] + fb0[2]*fb0[2] + fb0[3]*fb0[3]
         + fb1[0]*fb1[0] + fb1[1]*fb1[1] + fb1[2]*fb1[2] + fb1[3]*fb1[3];

    bf16x8 A0, A1;
    A0[0] = bf16s(fa0[0]); A0[1] = bf16s(fa0[1]); A0[2] = bf16s(fa0[2]); A0[3] = bf16s(fa0[3]);
    A0[4] = bf16s(fa1[0]); A0[5] = bf16s(fa1[1]); A0[6] = bf16s(fa1[2]); A0[7] = bf16s(fa1[3]);
    A1[0] = bf16s(fb0[0]); A1[1] = bf16s(fb0[1]); A1[2] = bf16s(fb0[2]); A1[3] = bf16s(fb0[3]);
    A1[4] = bf16s(fb1[0]); A1[5] = bf16s(fb1[1]); A1[6] = bf16s(fb1[2]); A1[7] = bf16s(fb1[3]);

    #pragma unroll
    for (int t = 0; t < NT; ++t) {
      const bf16x8 Bf = *(const bf16x8*)(protoB + (size_t)(t * 16 + lr) * DIM + koff);
      acc0[t] = __builtin_amdgcn_mfma_f32_16x16x32_bf16(A0, Bf, acc0[t], 0, 0, 0);
      acc1[t] = __builtin_amdgcn_mfma_f32_16x16x32_bf16(A1, Bf, acc1[t], 0, 0, 0);
    }
  }

  // f2 held per (lr = sample row); reduce across the 4 k-groups
  f2a += __shfl_xor(f2a, 16); f2a += __shfl_xor(f2a, 32);
  f2b += __shfl_xor(f2b, 16); f2b += __shfl_xor(f2b, 32);

  float p2v[NT];
  #pragma unroll
  for (int t = 0; t < NT; ++t) p2v[t] = p2[t * 16 + lr];

  float lsum = 0.f;
  #pragma unroll
  for (int m = 0; m < 2; ++m) {
    #pragma unroll
    for (int r = 0; r < 4; ++r) {
      const int srow = kg * 4 + r;                  // C/D row = local sample
      const float f2s = __shfl(m == 0 ? f2a : f2b, srow);
      const int samp = base + m * 16 + srow;
      const int lab = labels[samp];
      float bestd = 1e38f; int bestc = 1 << 30;
      float posd = -1.f;
      #pragma unroll
      for (int t = 0; t < NT; ++t) {
        const int cidx = t * 16 + lr;               // C/D col = class
        const float s = (m == 0) ? acc0[t][r] : acc1[t][r];
        const float d2 = fmaxf(f2s + p2v[t] - 2.0f * s, 0.0f);
        if (cidx == lab) posd = d2;
        else if (cidx < NCLS &&
                 (d2 < bestd || (d2 == bestd && cidx < bestc))) { bestd = d2; bestc = cidx; }
      }
      // reduce across the 16 lanes of this row-group (xor stays within group)
      #pragma unroll
      for (int sft = 1; sft < 16; sft <<= 1) {
        const float od = __shfl_xor(bestd, sft);
        const int   oc = __shfl_xor(bestc, sft);
        const float op = __shfl_xor(posd, sft);
        if (od < bestd || (od == bestd && oc < bestc)) { bestd = od; bestc = oc; }
        posd = fmaxf(posd, op);
      }
      const float dap = posd, dan = bestd;
      const float dapn = dap / (dap + dan + 1e-8f);
      const float dann = dan / (dapn + dan + 1e-8f);   // sequential normalization
      const float ps = fmaxf(0.f, 1.5f * dapn - 0.8f * dann + 0.6f);
      if (lr == 0) lsum += ps;   // one lane per row-group accumulates
    }
  }
  lsum += __shfl_xor(lsum, 16);
  lsum += __shfl_xor(lsum, 32);
  if (lane == 0) partials[wid] = lsum;
}

// ---------------- Kernel 3: deterministic final reduce -------------------------
__global__ __launch_bounds__(256) void k_finish(const float* __restrict__ partials,
                                                float* __restrict__ out)
{
  __shared__ float red[256];
  const int tid = threadIdx.x;
  red[tid] = partials[tid] + partials[tid + 256] + partials[tid + 512] + partials[tid + 768];
  __syncthreads();
  for (int s = 128; s > 0; s >>= 1) {
    if (tid < s) red[tid] += red[tid + s];
    __syncthreads();
  }
  if (tid == 0) out[0] = fabsf(0.2f * (red[0] / (float)NSAMP));
}

extern "C" void kernel_launch(void* const* d_in, const int* in_sizes, int n_in,
                              void* d_out, int out_size, void* d_ws, size_t ws_size,
                              hipStream_t stream) {
  const float* feat = (const float*)d_in[0];
  const int* labels = (const int*)d_in[1];
  float* out = (float*)d_out;

  char* ws = (char*)d_ws;
  unsigned short* protoB = (unsigned short*)ws;                 // 208*512*2 = 212992 B
  float* p2 = (float*)(ws + NPAD * DIM * 2);                    // 832 B
  float* partials = (float*)(ws + NPAD * DIM * 2 + 1024);       // 1024 floats

  k_proto<<<NPAD, 256, 0, stream>>>(feat, labels, protoB, p2);
  k_score<<<256, 256, 0, stream>>>(feat, labels, protoB, p2, partials);
  k_finish<<<1, 256, 0, stream>>>(partials, out);
}

// Round 2
// 67.617 us; speedup vs baseline: 1.5910x; 1.5910x over previous
//
#include <hip/hip_runtime.h>
#include <hip/hip_bf16.h>

#define NCLS 200
#define NPAD 208
#define NT 13          // 208 / 16 class tiles
#define DIM 512
#define NSAMP 32768
#define CAP 96         // per-wave list capacity (expect ~20.5 +- 4.5)

typedef __attribute__((ext_vector_type(4))) float f32x4;
typedef __attribute__((ext_vector_type(4))) int   i32x4;
typedef __attribute__((ext_vector_type(8))) short bf16x8;

__device__ inline short bf16s(float x) {
  __hip_bfloat16 h = __float2bfloat16(x);
  return *reinterpret_cast<short*>(&h);
}

// ---------------- Kernel 1: per-class prototypes (segment mean) ----------------
// One block per class, 512 threads = 8 waves. Wave w owns samples
// [w*4096, (w+1)*4096): builds its private match list via barrier-free
// intra-wave ballot ranking, then gathers+sums those rows (lane = 8 dims).
// Single barrier at the end combines 8 per-wave partials in fixed order.
__global__ __launch_bounds__(512) void k_proto(
    const float* __restrict__ feat, const int* __restrict__ labels,
    unsigned short* __restrict__ protoB, float* __restrict__ p2out)
{
  const int c = blockIdx.x;
  const int tid = threadIdx.x;
  if (c >= NCLS) {
    protoB[c * DIM + tid] = 0;        // bf16 +0.0
    if (tid == 0) p2out[c] = 1e30f;   // never wins argmin
    return;
  }
  __shared__ int   lists[8][CAP];
  __shared__ int   cnts[8];
  __shared__ float partial[8][DIM];
  __shared__ float red[512];

  const int lane = tid & 63;
  const int w = tid >> 6;

  // phase 1: barrier-free per-wave match list (fixed order within wave)
  int cnt = 0;
  const int segbase = w * (NSAMP / 8);
  for (int i = 0; i < (NSAMP / 8) / 256; ++i) {           // 16 iters
    const int base = segbase + i * 256 + lane * 4;
    const i32x4 lab4 = *(const i32x4*)(labels + base);
    #pragma unroll
    for (int u = 0; u < 4; ++u) {
      const bool m = (lab4[u] == c);
      const unsigned long long bal = __ballot(m);
      if (m) {
        const int pos = cnt + __popcll(bal & ((1ull << lane) - 1ull));
        if (pos < CAP) lists[w][pos] = base + u;
      }
      cnt += __popcll(bal);
    }
  }
  if (cnt > CAP) cnt = CAP;
  if (lane == 0) cnts[w] = cnt;

  // phase 2: gather-sum this wave's rows; lane owns dims [lane*8, lane*8+8)
  float acc[8];
  #pragma unroll
  for (int q = 0; q < 8; ++q) acc[q] = 0.f;
  for (int j = 0; j < cnt; ++j) {
    const int r = lists[w][j];
    const f32x4 a = *(const f32x4*)(feat + (size_t)r * DIM + lane * 8);
    const f32x4 b = *(const f32x4*)(feat + (size_t)r * DIM + lane * 8 + 4);
    acc[0] += a[0]; acc[1] += a[1]; acc[2] += a[2]; acc[3] += a[3];
    acc[4] += b[0]; acc[5] += b[1]; acc[6] += b[2]; acc[7] += b[3];
  }
  #pragma unroll
  for (int q = 0; q < 8; ++q) partial[w][lane * 8 + q] = acc[q];
  __syncthreads();

  // phase 3: combine 8 wave partials in fixed order; thread owns dim = tid
  int total = 0;
  #pragma unroll
  for (int u = 0; u < 8; ++u) total += cnts[u];
  float s = 0.f;
  #pragma unroll
  for (int u = 0; u < 8; ++u) s += partial[u][tid];
  const float p = s / ((float)total + 1e-8f);   // counts + EPS
  protoB[c * DIM + tid] = (unsigned short)bf16s(p);

  red[tid] = p * p;
  __syncthreads();
  for (int st = 256; st > 0; st >>= 1) {
    if (tid < st) red[tid] += red[tid + st];
    __syncthreads();
  }
  if (tid == 0) p2out[c] = red[0];
}

// ---------------- Kernel 2: scores (MFMA GEMM) + argmin + per-sample loss ------
// 1024 waves; each wave: 32 samples (2 x 16-row tiles) x 208 classes.
// A = features (fp32 loaded, bf16 in-register), B = bf16 prototypes, f2 on the fly.
__global__ __launch_bounds__(256) void k_score(
    const float* __restrict__ feat, const int* __restrict__ labels,
    const unsigned short* __restrict__ protoB, const float* __restrict__ p2,
    float* __restrict__ partials)
{
  const int tid = threadIdx.x;
  const int lane = tid & 63;
  const int wid = blockIdx.x * 4 + (tid >> 6);   // 0..1023
  const int base = wid * 32;
  const int lr = lane & 15;    // A row / B col (local)
  const int kg = lane >> 4;    // k-group

  f32x4 acc0[NT], acc1[NT];
  #pragma unroll
  for (int t = 0; t < NT; ++t) {
    acc0[t] = f32x4{0.f, 0.f, 0.f, 0.f};
    acc1[t] = f32x4{0.f, 0.f, 0.f, 0.f};
  }
  float f2a = 0.f, f2b = 0.f;

  const float* arow0 = feat + (size_t)(base + lr) * DIM;
  const float* arow1 = arow0 + 16 * DIM;

  for (int k = 0; k < 16; ++k) {
    const int koff = k * 32 + kg * 8;
    const f32x4 fa0 = *(const f32x4*)(arow0 + koff);
    const f32x4 fa1 = *(const f32x4*)(arow0 + koff + 4);
    const f32x4 fb0 = *(const f32x4*)(arow1 + koff);
    const f32x4 fb1 = *(const f32x4*)(arow1 + koff + 4);

    f2a += fa0[0]*fa0[0] + fa0[1]*fa0[1] + fa0[2]*fa0[2] + fa0[3]*fa0[3]
         + fa1[0]*fa1[0] + fa1[1]*fa1[1] + fa1[2]*fa1[2] + fa1[3]*fa1[3];
    f2b += fb0[0]*fb0[0] + fb0[1]*fb0[1] + fb0[2]*fb0[2] + fb0[3]*fb0[3]
         + fb1[0]*fb1[0] + fb1[1]*fb1[1] + fb1[2]*fb1[2] + fb1[3]*fb1[3];

    bf16x8 A0, A1;
    A0[0] = bf16s(fa0[0]); A0[1] = bf16s(fa0[1]); A0[2] = bf16s(fa0[2]); A0[3] = bf16s(fa0[3]);
    A0[4] = bf16s(fa1[0]); A0[5] = bf16s(fa1[1]); A0[6] = bf16s(fa1[2]); A0[7] = bf16s(fa1[3]);
    A1[0] = bf16s(fb0[0]); A1[1] = bf16s(fb0[1]); A1[2] = bf16s(fb0[2]); A1[3] = bf16s(fb0[3]);
    A1[4] = bf16s(fb1[0]); A1[5] = bf16s(fb1[1]); A1[6] = bf16s(fb1[2]); A1[7] = bf16s(fb1[3]);

    #pragma unroll
    for (int t = 0; t < NT; ++t) {
      const bf16x8 Bf = *(const bf16x8*)(protoB + (size_t)(t * 16 + lr) * DIM + koff);
      acc0[t] = __builtin_amdgcn_mfma_f32_16x16x32_bf16(A0, Bf, acc0[t], 0, 0, 0);
      acc1[t] = __builtin_amdgcn_mfma_f32_16x16x32_bf16(A1, Bf, acc1[t], 0, 0, 0);
    }
  }

  // f2 held per (lr = sample row); reduce across the 4 k-groups
  f2a += __shfl_xor(f2a, 16); f2a += __shfl_xor(f2a, 32);
  f2b += __shfl_xor(f2b, 16); f2b += __shfl_xor(f2b, 32);

  float p2v[NT];
  #pragma unroll
  for (int t = 0; t < NT; ++t) p2v[t] = p2[t * 16 + lr];

  float lsum = 0.f;
  #pragma unroll
  for (int m = 0; m < 2; ++m) {
    #pragma unroll
    for (int r = 0; r < 4; ++r) {
      const int srow = kg * 4 + r;                  // C/D row = local sample
      const float f2s = __shfl(m == 0 ? f2a : f2b, srow);
      const int samp = base + m * 16 + srow;
      const int lab = labels[samp];
      float bestd = 1e38f; int bestc = 1 << 30;
      float posd = -1.f;
      #pragma unroll
      for (int t = 0; t < NT; ++t) {
        const int cidx = t * 16 + lr;               // C/D col = class
        const float s = (m == 0) ? acc0[t][r] : acc1[t][r];
        const float d2 = fmaxf(f2s + p2v[t] - 2.0f * s, 0.0f);
        if (cidx == lab) posd = d2;
        else if (cidx < NCLS &&
                 (d2 < bestd || (d2 == bestd && cidx < bestc))) { bestd = d2; bestc = cidx; }
      }
      // reduce across the 16 lanes of this row-group (xor stays within group)
      #pragma unroll
      for (int sft = 1; sft < 16; sft <<= 1) {
        const float od = __shfl_xor(bestd, sft);
        const int   oc = __shfl_xor(bestc, sft);
        const float op = __shfl_xor(posd, sft);
        if (od < bestd || (od == bestd && oc < bestc)) { bestd = od; bestc = oc; }
        posd = fmaxf(posd, op);
      }
      const float dap = posd, dan = bestd;
      const float dapn = dap / (dap + dan + 1e-8f);
      const float dann = dan / (dapn + dan + 1e-8f);   // sequential normalization
      const float ps = fmaxf(0.f, 1.5f * dapn - 0.8f * dann + 0.6f);
      if (lr == 0) lsum += ps;   // one lane per row-group accumulates
    }
  }
  lsum += __shfl_xor(lsum, 16);
  lsum += __shfl_xor(lsum, 32);
  if (lane == 0) partials[wid] = lsum;
}

// ---------------- Kernel 3: deterministic final reduce -------------------------
__global__ __launch_bounds__(256) void k_finish(const float* __restrict__ partials,
                                                float* __restrict__ out)
{
  __shared__ float red[256];
  const int tid = threadIdx.x;
  red[tid] = partials[tid] + partials[tid + 256] + partials[tid + 512] + partials[tid + 768];
  __syncthreads();
  for (int s = 128; s > 0; s >>= 1) {
    if (tid < s) red[tid] += red[tid + s];
    __syncthreads();
  }
  if (tid == 0) out[0] = fabsf(0.2f * (red[0] / (float)NSAMP));
}

extern "C" void kernel_launch(void* const* d_in, const int* in_sizes, int n_in,
                              void* d_out, int out_size, void* d_ws, size_t ws_size,
                              hipStream_t stream) {
  const float* feat = (const float*)d_in[0];
  const int* labels = (const int*)d_in[1];
  float* out = (float*)d_out;

  char* ws = (char*)d_ws;
  unsigned short* protoB = (unsigned short*)ws;                 // 208*512*2 = 212992 B
  float* p2 = (float*)(ws + NPAD * DIM * 2);                    // 832 B
  float* partials = (float*)(ws + NPAD * DIM * 2 + 1024);       // 1024 floats

  k_proto<<<NPAD, 512, 0, stream>>>(feat, labels, protoB, p2);
  k_score<<<256, 256, 0, stream>>>(feat, labels, protoB, p2, partials);
  k_finish<<<1, 256, 0, stream>>>(partials, out);
}